// Round 5
// baseline (692.673 us; speedup 1.0000x reference)
//
#include <hip/hip_runtime.h>
#include <cstdint>
#include <cstddef>

#define N_USER 100000
#define N_ITEM 50000
#define CDIM   128
#define NEDGE  600000
#define N_SEG  (N_ITEM + N_USER)          // item segments first, then user
#define NB_SCAN ((N_SEG + 255) / 256)     // 586 scan blocks

// XCD-sliced fill parameters
#define FILL_EPB 2048                           // edges per block-chunk
#define FILL_NCHUNK ((NEDGE + FILL_EPB - 1) / FILL_EPB)   // 293
#define SLICE_DIV ((N_SEG + 7) / 8)             // 18750 segments per slice

typedef __bf16 bf16_t;
typedef bf16_t bfvec8 __attribute__((ext_vector_type(8)));
typedef bf16_t bfvec4 __attribute__((ext_vector_type(4)));
typedef float  f32x4  __attribute__((ext_vector_type(4)));

// LDS row stride for 128-wide bf16 tiles: 136 elems = 272 B (16B-aligned rows).
#define LDW 136

// ---------------------------------------------------------------------------
// One-time: transpose+cvt all 10 weight matrices (W_init[2], mlp_W[8]) from
// fp32 [k][n] to bf16 [n][k] in ws.
// ---------------------------------------------------------------------------
__global__ __launch_bounds__(256) void prep_weights(
    const float* __restrict__ W_init, const float* __restrict__ mlp_W,
    bf16_t* __restrict__ wtg)
{
    int m  = blockIdx.x >> 6;            // 10 matrices x 64 blocks
    int it = blockIdx.x & 63;
    const float* src = (m < 2) ? (W_init + (size_t)m * 16384)
                               : (mlp_W + (size_t)(m - 2) * 16384);
    int e = it * 256 + threadIdx.x;      // e = n*128 + k
    int n = e >> 7, k = e & 127;
    wtg[(size_t)m * 16384 + e] = (bf16_t)src[k * 128 + n];
}

// Vectorized stage: pre-transposed bf16 weight [n][k] -> LDS padded rows.
template <int NT>
static __device__ inline void stage_wbf(bf16_t* Wt, const bf16_t* __restrict__ Wg, int tid) {
    #pragma unroll
    for (int c = tid; c < 2048; c += NT) {
        int n = c >> 4, koff = (c & 15) * 8;
        *reinterpret_cast<bfvec8*>(&Wt[n * LDW + koff]) =
            *reinterpret_cast<const bfvec8*>(&Wg[n * 128 + koff]);
    }
}

// ---------------------------------------------------------------------------
// Init GEMM, swapped operands (proven): lane holds 4 consecutive output cols
// of its own row => vector stores. 512 thr, wave w owns rows w*16..+15.
// ---------------------------------------------------------------------------
__global__ __launch_bounds__(512) void gemm_init(
    const float* __restrict__ X,
    const bf16_t* __restrict__ Wg,     // pre-transposed bf16 [n][k]
    const float* __restrict__ B,
    bf16_t* __restrict__ Y, int M)
{
    __shared__ __align__(16) bf16_t Wt[128 * LDW];
    const int tid = threadIdx.x;
    stage_wbf<512>(Wt, Wg, tid);
    __syncthreads();

    const int wave = tid >> 6, lane = tid & 63;
    const int quad = lane >> 4, ln16 = lane & 15;
    const int row_l = wave * 16 + ln16;
    const int rowg = blockIdx.x * 128 + row_l;
    const int rowc = rowg < M ? rowg : 0;

    bfvec8 xb[4];
    const float* xp = X + (size_t)rowc * CDIM + quad * 8;
    #pragma unroll
    for (int kc = 0; kc < 4; ++kc) {
        f32x4 lo = *reinterpret_cast<const f32x4*>(xp + kc * 32);
        f32x4 hi = *reinterpret_cast<const f32x4*>(xp + kc * 32 + 4);
        #pragma unroll
        for (int j = 0; j < 4; ++j) {
            xb[kc][j]     = (bf16_t)lo[j];
            xb[kc][j + 4] = (bf16_t)hi[j];
        }
    }

    f32x4 acc[8];
    #pragma unroll
    for (int t = 0; t < 8; ++t) acc[t] = (f32x4){0.f, 0.f, 0.f, 0.f};
    #pragma unroll
    for (int t = 0; t < 8; ++t) {
        const bf16_t* wp = &Wt[(t * 16 + ln16) * LDW + quad * 8];
        #pragma unroll
        for (int kc = 0; kc < 4; ++kc) {
            bfvec8 wv = *reinterpret_cast<const bfvec8*>(wp + kc * 32);
            acc[t] = __builtin_amdgcn_mfma_f32_16x16x32_bf16(wv, xb[kc], acc[t], 0, 0, 0);
        }
    }

    if (rowg < M) {
        #pragma unroll
        for (int t = 0; t < 8; ++t) {
            f32x4 bv = *reinterpret_cast<const f32x4*>(&B[t * 16 + quad * 4]);
            bfvec4 o;
            #pragma unroll
            for (int r = 0; r < 4; ++r) o[r] = (bf16_t)(acc[t][r] + bv[r]);
            *reinterpret_cast<bfvec4*>(&Y[(size_t)rowg * CDIM + t * 16 + quad * 4]) = o;
        }
    }
}

// ---------------------------------------------------------------------------
// CSR build pieces
// ---------------------------------------------------------------------------
__global__ __launch_bounds__(256) void zero_i32(int* __restrict__ p, int n)
{
    int i = blockIdx.x * 256 + threadIdx.x;
    if (i < n) p[i] = 0;
}

__global__ __launch_bounds__(256) void hist_rank(
    const int* __restrict__ edge_ui, const int* __restrict__ edge_iu,
    int* __restrict__ deg, int2* __restrict__ rank2)
{
    int i = blockIdx.x * 256 + threadIdx.x;
    if (i >= NEDGE) return;
    int r0 = atomicAdd(&deg[edge_ui[NEDGE + i]], 1);
    int r1 = atomicAdd(&deg[N_ITEM + edge_iu[NEDGE + i]], 1);
    rank2[i] = make_int2(r0, r1);
}

__global__ __launch_bounds__(256) void block_scan(
    int* __restrict__ off, int* __restrict__ bsum, int n)
{
    __shared__ int sh[256];
    int tid = threadIdx.x;
    int i = blockIdx.x * 256 + tid;
    int v = (i < n) ? off[i] : 0;
    sh[tid] = v;
    __syncthreads();
    #pragma unroll
    for (int d = 1; d < 256; d <<= 1) {
        int t = (tid >= d) ? sh[tid - d] : 0;
        __syncthreads();
        sh[tid] += t;
        __syncthreads();
    }
    if (i < n) off[i] = sh[tid] - v;
    if (tid == 255) bsum[blockIdx.x] = sh[255];
}

__global__ __launch_bounds__(1024) void scan_bsums(int* __restrict__ bsum)
{
    __shared__ int sh[1024];
    int tid = threadIdx.x;
    int v = (tid < NB_SCAN) ? bsum[tid] : 0;
    sh[tid] = v;
    __syncthreads();
    #pragma unroll
    for (int d = 1; d < 1024; d <<= 1) {
        int t = (tid >= d) ? sh[tid - d] : 0;
        __syncthreads();
        sh[tid] += t;
        __syncthreads();
    }
    if (tid < NB_SCAN) bsum[tid] = sh[tid] - v;
    if (tid == 1023) bsum[NB_SCAN] = sh[1023];
}

__global__ __launch_bounds__(256) void add_offsets(
    int* __restrict__ off, const int* __restrict__ bsum, int n)
{
    int i = blockIdx.x * 256 + threadIdx.x;
    if (i < n) off[i] += bsum[i >> 8];
    else if (i == n) off[n] = bsum[NB_SCAN];
}

// ---------------------------------------------------------------------------
// Atomic-free, XCD-sliced CSR fill (proven R1).
// ---------------------------------------------------------------------------
__global__ __launch_bounds__(256) void fill_sliced(
    const int* __restrict__ edge_ui, const int* __restrict__ edge_iu,
    const int* __restrict__ off, const int2* __restrict__ rank2,
    int* __restrict__ srcbuf)
{
    const int r = blockIdx.x & 7;
    const int chunk = blockIdx.x >> 3;
    const int base = chunk * FILL_EPB + threadIdx.x;
    #pragma unroll
    for (int j = 0; j < FILL_EPB / 256; ++j) {
        int i = base + j * 256;
        if (i < NEDGE) {
            int d0 = edge_ui[NEDGE + i];            // item dst; seg = d0
            int d1 = edge_iu[NEDGE + i] + N_ITEM;   // user dst; seg index
            int2 rk = rank2[i];
            if (d0 / SLICE_DIV == r)
                srcbuf[off[d0] + rk.x] = edge_ui[i];
            if (d1 / SLICE_DIV == r)
                srcbuf[off[d1] + rk.y] = edge_iu[i];
        }
    }
}

// ---------------------------------------------------------------------------
// FUSED layer: gather + GIN combine + MLP(2x linear/ReLU) + LayerNorm + ReLU.
// 512 thr, 128 dst rows/block (one node type per block). Wave w owns rows
// w*16..+15. Phase A: gather each row with 4 groups x 16 lanes x bfvec8
// (proven R3 loop), combine (1+eps)*x + agg, write bf16 row into At (LDS).
// Phase B: GEMM1/GEMM2/LN exactly as proven mlp path — each lane reads and
// writes only its OWN row of At, so no cross-wave LDS hazard; barriers only
// around the shared Wt re-stage. MFMA work of one resident block overlaps
// the other block's gather latency (2 blocks/CU). In-place race avoided by
// ping-pong buffers (caller).
// ---------------------------------------------------------------------------
__global__ __launch_bounds__(512) void gin_layer(
    const bf16_t* __restrict__ xu_in, const bf16_t* __restrict__ xi_in,
    const float* __restrict__ eps2,            // eps + 2*l: [item, user]
    const int* __restrict__ off_all, const int* __restrict__ srcbuf,
    const bf16_t* __restrict__ wg,    // this layer: [itemW1,itemW2,userW1,userW2] bf16 [n][k]
    const float* __restrict__ mlpb,   // mlp_b + l*4*128
    const float* __restrict__ lng,    // ln_g + l*2*128
    const float* __restrict__ lnb,    // ln_b + l*2*128
    bf16_t* __restrict__ yib, bf16_t* __restrict__ yub,   // bf16 outs (l=0)
    float* __restrict__ xif, float* __restrict__ xuf,     // fp32 outs (l=1)
    int f32out)
{
    __shared__ __align__(16) bf16_t Wt[128 * LDW];
    __shared__ __align__(16) bf16_t At[128 * LDW];

    const int gBI = (N_ITEM + 127) / 128;
    int b = blockIdx.x;
    bool isItem = b < gBI;
    int M  = isItem ? N_ITEM : N_USER;
    int bx = isItem ? b : b - gBI;

    const bfvec8* F = reinterpret_cast<const bfvec8*>(isItem ? xu_in : xi_in);
    const bfvec8* X = reinterpret_cast<const bfvec8*>(isItem ? xi_in : xu_in);
    const int* off = isItem ? off_all : off_all + N_ITEM;
    bf16_t* Yb     = isItem ? yib : yub;
    float*  Yf     = isItem ? xif : xuf;
    float s = 1.f + (isItem ? eps2[0] : eps2[1]);

    // edge type 0 = (user->item) => item dst; 1 = (item->user) => user dst
    const bf16_t* W1 = wg + (isItem ? 0 : 2) * 16384;
    const bf16_t* W2 = W1 + 16384;
    const float* B1 = mlpb + (isItem ? 0 : 2) * 128;
    const float* B2 = B1 + 128;
    // node type 0 = user, 1 = item
    const float* G  = lng + (isItem ? 128 : 0);
    const float* Bb = lnb + (isItem ? 128 : 0);

    const int tid = threadIdx.x;
    stage_wbf<512>(Wt, W1, tid);       // no barrier yet: gather doesn't touch Wt

    const int wave = tid >> 6, lane = tid & 63;
    const int quad = lane >> 4, ln16 = lane & 15;   // quad doubles as gather grp
    const int rowBase = bx * 128;

    // ---- Phase A: gather wave's 16 rows into At ----
    for (int rr = 0; rr < 16; ++rr) {
        int rowl = wave * 16 + rr;
        int node = rowBase + rowl;
        float acc[8];
        #pragma unroll
        for (int j = 0; j < 8; ++j) acc[j] = 0.f;

        if (node < M) {
            int start = off[node], end = off[node + 1];
            int e = start + quad;
            for (; e + 12 < end; e += 16) {
                int s0 = srcbuf[e];
                int s1 = srcbuf[e + 4];
                int s2 = srcbuf[e + 8];
                int s3 = srcbuf[e + 12];
                bfvec8 v0 = F[(size_t)s0 * 16 + ln16];
                bfvec8 v1 = F[(size_t)s1 * 16 + ln16];
                bfvec8 v2 = F[(size_t)s2 * 16 + ln16];
                bfvec8 v3 = F[(size_t)s3 * 16 + ln16];
                #pragma unroll
                for (int j = 0; j < 8; ++j)
                    acc[j] += ((float)v0[j] + (float)v1[j]) + ((float)v2[j] + (float)v3[j]);
            }
            for (; e + 4 < end; e += 8) {
                int s0 = srcbuf[e];
                int s1 = srcbuf[e + 4];
                bfvec8 v0 = F[(size_t)s0 * 16 + ln16];
                bfvec8 v1 = F[(size_t)s1 * 16 + ln16];
                #pragma unroll
                for (int j = 0; j < 8; ++j) acc[j] += (float)v0[j] + (float)v1[j];
            }
            for (; e < end; e += 4) {
                bfvec8 v = F[(size_t)srcbuf[e] * 16 + ln16];
                #pragma unroll
                for (int j = 0; j < 8; ++j) acc[j] += (float)v[j];
            }
        }

        // cross-group reduce (groups differ in lane bits 4..5)
        #pragma unroll
        for (int j = 0; j < 8; ++j) {
            acc[j] += __shfl_xor(acc[j], 16, 64);
            acc[j] += __shfl_xor(acc[j], 32, 64);
        }

        if (quad == 0) {
            bfvec8 o;
            if (node < M) {
                bfvec8 xv = X[(size_t)node * 16 + ln16];
                #pragma unroll
                for (int j = 0; j < 8; ++j) o[j] = (bf16_t)(s * (float)xv[j] + acc[j]);
            } else {
                #pragma unroll
                for (int j = 0; j < 8; ++j) o[j] = (bf16_t)0.f;
            }
            *reinterpret_cast<bfvec8*>(&At[rowl * LDW + ln16 * 8]) = o;
        }
    }
    __syncthreads();     // Wt staged + all At rows gathered

    const int row_l = wave * 16 + ln16;
    const int rowg = rowBase + row_l;

    // ---- GEMM1: relu(At@W1+b1) -> At (each lane: own row only) ----
    bfvec8 xb[4];
    #pragma unroll
    for (int kc = 0; kc < 4; ++kc)
        xb[kc] = *reinterpret_cast<const bfvec8*>(&At[row_l * LDW + kc * 32 + quad * 8]);

    f32x4 acc[8];
    #pragma unroll
    for (int t = 0; t < 8; ++t) acc[t] = (f32x4){0.f, 0.f, 0.f, 0.f};
    #pragma unroll
    for (int t = 0; t < 8; ++t) {
        const bf16_t* wp = &Wt[(t * 16 + ln16) * LDW + quad * 8];
        #pragma unroll
        for (int kc = 0; kc < 4; ++kc) {
            bfvec8 wv = *reinterpret_cast<const bfvec8*>(wp + kc * 32);
            acc[t] = __builtin_amdgcn_mfma_f32_16x16x32_bf16(wv, xb[kc], acc[t], 0, 0, 0);
        }
    }

    #pragma unroll
    for (int t = 0; t < 8; ++t) {
        f32x4 bv = *reinterpret_cast<const f32x4*>(&B1[t * 16 + quad * 4]);
        bfvec4 o;
        #pragma unroll
        for (int r = 0; r < 4; ++r) {
            float v = acc[t][r] + bv[r];
            o[r] = (bf16_t)(v > 0.f ? v : 0.f);
        }
        *reinterpret_cast<bfvec4*>(&At[row_l * LDW + t * 16 + quad * 4]) = o;
    }
    __syncthreads();
    stage_wbf<512>(Wt, W2, tid);       // overwrite W1; all GEMM1 Wt reads done
    __syncthreads();

    // ---- GEMM2 + bias + ReLU + LayerNorm + ReLU -> Y ----
    bfvec8 hb[4];
    #pragma unroll
    for (int kc = 0; kc < 4; ++kc)
        hb[kc] = *reinterpret_cast<const bfvec8*>(&At[row_l * LDW + kc * 32 + quad * 8]);

    #pragma unroll
    for (int t = 0; t < 8; ++t) acc[t] = (f32x4){0.f, 0.f, 0.f, 0.f};
    #pragma unroll
    for (int t = 0; t < 8; ++t) {
        const bf16_t* wp = &Wt[(t * 16 + ln16) * LDW + quad * 8];
        #pragma unroll
        for (int kc = 0; kc < 4; ++kc) {
            bfvec8 wv = *reinterpret_cast<const bfvec8*>(wp + kc * 32);
            acc[t] = __builtin_amdgcn_mfma_f32_16x16x32_bf16(wv, hb[kc], acc[t], 0, 0, 0);
        }
    }

    #pragma unroll
    for (int t = 0; t < 8; ++t) {
        f32x4 bv = *reinterpret_cast<const f32x4*>(&B2[t * 16 + quad * 4]);
        #pragma unroll
        for (int r = 0; r < 4; ++r) {
            float v = acc[t][r] + bv[r];
            acc[t][r] = v > 0.f ? v : 0.f;     // ReLU after 2nd linear
        }
    }

    // LN over this lane's own row: 32 in-lane values + 2 shuffles
    float sm = 0.f;
    #pragma unroll
    for (int t = 0; t < 8; ++t)
        #pragma unroll
        for (int r = 0; r < 4; ++r) sm += acc[t][r];
    sm += __shfl_xor(sm, 16, 64);
    sm += __shfl_xor(sm, 32, 64);
    float mean = sm * (1.f / 128.f);
    float sq = 0.f;
    #pragma unroll
    for (int t = 0; t < 8; ++t)
        #pragma unroll
        for (int r = 0; r < 4; ++r) { float d = acc[t][r] - mean; sq += d * d; }
    sq += __shfl_xor(sq, 16, 64);
    sq += __shfl_xor(sq, 32, 64);
    float rs = rsqrtf(sq * (1.f / 128.f) + 1e-5f);

    if (rowg < M) {
        if (f32out) {
            #pragma unroll
            for (int t = 0; t < 8; ++t) {
                f32x4 g4 = *reinterpret_cast<const f32x4*>(&G[t * 16 + quad * 4]);
                f32x4 b4 = *reinterpret_cast<const f32x4*>(&Bb[t * 16 + quad * 4]);
                f32x4 y;
                #pragma unroll
                for (int r = 0; r < 4; ++r) {
                    float v = (acc[t][r] - mean) * rs * g4[r] + b4[r];
                    y[r] = v > 0.f ? v : 0.f;
                }
                *reinterpret_cast<f32x4*>(&Yf[(size_t)rowg * CDIM + t * 16 + quad * 4]) = y;
            }
        } else {
            #pragma unroll
            for (int t = 0; t < 8; ++t) {
                f32x4 g4 = *reinterpret_cast<const f32x4*>(&G[t * 16 + quad * 4]);
                f32x4 b4 = *reinterpret_cast<const f32x4*>(&Bb[t * 16 + quad * 4]);
                bfvec4 y;
                #pragma unroll
                for (int r = 0; r < 4; ++r) {
                    float v = (acc[t][r] - mean) * rs * g4[r] + b4[r];
                    y[r] = (bf16_t)(v > 0.f ? v : 0.f);
                }
                *reinterpret_cast<bfvec4*>(&Yb[(size_t)rowg * CDIM + t * 16 + quad * 4]) = y;
            }
        }
    }
}

// ---------------------------------------------------------------------------
extern "C" void kernel_launch(void* const* d_in, const int* in_sizes, int n_in,
                              void* d_out, int out_size, void* d_ws, size_t ws_size,
                              hipStream_t stream)
{
    const float* x_user = (const float*)d_in[0];
    const float* x_item = (const float*)d_in[1];
    const float* W_init = (const float*)d_in[2];
    const float* b_init = (const float*)d_in[3];
    const float* mlp_W  = (const float*)d_in[4];
    const float* mlp_b  = (const float*)d_in[5];
    const float* eps    = (const float*)d_in[6];
    const float* ln_g   = (const float*)d_in[7];
    const float* ln_b   = (const float*)d_in[8];
    const int* edge_ui  = (const int*)d_in[9];
    const int* edge_iu  = (const int*)d_in[10];

    // final fp32 outputs
    float* xuf = (float*)d_out;                     // [N_USER,128]
    float* xif = xuf + (size_t)N_USER * CDIM;       // [N_ITEM,128]

    // ws: bf16 activations + CSR + pre-transposed weights
    char* w = (char*)d_ws;
    bf16_t* xub = (bf16_t*)w;                                  // 25.6 MB
    bf16_t* xib = xub + (size_t)N_USER * CDIM;                 // 12.8 MB
    bf16_t* tub = xib + (size_t)N_ITEM * CDIM;                 // 25.6 MB
    bf16_t* tib = tub + (size_t)N_USER * CDIM;                 // 12.8 MB
    int* off_all = (int*)(tib + (size_t)N_ITEM * CDIM);        // N_SEG+1
    int* bsum    = off_all + (N_SEG + 4);
    int* srcbuf  = bsum + (NB_SCAN + 2);                       // 2*NEDGE
    bf16_t* wtg  = (bf16_t*)(srcbuf + 2 * NEDGE);              // 10*16384 bf16

    // rank2 aliases tub: live only hist_rank -> fill_sliced, before layer-0
    // gin_layer writes tub. 4.8 MB < 25.6 MB region. 8B-aligned.
    int2* rank2 = (int2*)tub;

    const int gU = (N_USER + 127) / 128;            // 782
    const int gI = (N_ITEM + 127) / 128;            // 391
    const int gSeg = (N_SEG + 256) / 256;
    const int gE = (NEDGE + 255) / 256;             // 2344

    // one-time weight transpose (needs only inputs)
    prep_weights<<<640, 256, 0, stream>>>(W_init, mlp_W, wtg);

    // CSR prep
    zero_i32<<<(N_SEG + 255) / 256, 256, 0, stream>>>(off_all, N_SEG);
    hist_rank<<<gE, 256, 0, stream>>>(edge_ui, edge_iu, off_all, rank2);
    block_scan<<<NB_SCAN, 256, 0, stream>>>(off_all, bsum, N_SEG);
    scan_bsums<<<1, 1024, 0, stream>>>(bsum);
    add_offsets<<<gSeg, 256, 0, stream>>>(off_all, bsum, N_SEG);
    fill_sliced<<<FILL_NCHUNK * 8, 256, 0, stream>>>(edge_ui, edge_iu, off_all, rank2, srcbuf);

    // initial projection -> bf16 ws
    gemm_init<<<gU, 512, 0, stream>>>(x_user, wtg,         b_init,       xub, N_USER);
    gemm_init<<<gI, 512, 0, stream>>>(x_item, wtg + 16384, b_init + 128, xib, N_ITEM);

    // layer 0: read xub/xib -> write tub/tib (bf16). layer 1: read tub/tib -> fp32 d_out.
    gin_layer<<<gI + gU, 512, 0, stream>>>(
        xub, xib, eps, off_all, srcbuf,
        wtg + (size_t)2 * 16384, mlp_b, ln_g, ln_b,
        tib, tub, xif, xuf, 0);
    gin_layer<<<gI + gU, 512, 0, stream>>>(
        tub, tib, eps + 2, off_all, srcbuf,
        wtg + (size_t)6 * 16384, mlp_b + 4 * 128, ln_g + 2 * 128, ln_b + 2 * 128,
        nullptr, nullptr, xif, xuf, 1);
}

// Round 6
// 626.209 us; speedup vs baseline: 1.1061x; 1.1061x over previous
//
#include <hip/hip_runtime.h>
#include <cstdint>
#include <cstddef>

#define N_USER 100000
#define N_ITEM 50000
#define CDIM   128
#define NEDGE  600000
#define N_SEG  (N_ITEM + N_USER)          // item segments first, then user
#define NB_SCAN ((N_SEG + 255) / 256)     // 586 scan blocks

#define GU 782                            // (N_USER+127)/128
#define GI 391                            // (N_ITEM+127)/128
#define GHIST ((NEDGE + 511) / 512)       // 1172
#define GBI8 (N_ITEM / 8)                 // 6250 gather item blocks (8 nodes/blk)
#define GBU8 (N_USER / 8)                 // 12500 gather user blocks

// XCD-sliced fill parameters
#define FILL_EPB 2048
#define FILL_NCHUNK ((NEDGE + FILL_EPB - 1) / FILL_EPB)   // 293
#define SLICE_DIV ((N_SEG + 7) / 8)

typedef __bf16 bf16_t;
typedef bf16_t bfvec8 __attribute__((ext_vector_type(8)));
typedef bf16_t bfvec4 __attribute__((ext_vector_type(4)));
typedef float  f32x4  __attribute__((ext_vector_type(4)));

#define LDW 136   // LDS row stride (elems) for 128-wide bf16 tiles

// ---------------------------------------------------------------------------
// One-time: transpose+cvt all 10 weight matrices to bf16 [n][k] in ws.
// ---------------------------------------------------------------------------
__global__ __launch_bounds__(256) void prep_weights(
    const float* __restrict__ W_init, const float* __restrict__ mlp_W,
    bf16_t* __restrict__ wtg)
{
    int m  = blockIdx.x >> 6;
    int it = blockIdx.x & 63;
    const float* src = (m < 2) ? (W_init + (size_t)m * 16384)
                               : (mlp_W + (size_t)(m - 2) * 16384);
    int e = it * 256 + threadIdx.x;      // e = n*128 + k
    int n = e >> 7, k = e & 127;
    wtg[(size_t)m * 16384 + e] = (bf16_t)src[k * 128 + n];
}

template <int NT>
static __device__ inline void stage_wbf(bf16_t* Wt, const bf16_t* __restrict__ Wg, int tid) {
    #pragma unroll
    for (int c = tid; c < 2048; c += NT) {
        int n = c >> 4, koff = (c & 15) * 8;
        *reinterpret_cast<bfvec8*>(&Wt[n * LDW + koff]) =
            *reinterpret_cast<const bfvec8*>(&Wg[n * 128 + koff]);
    }
}

// ---------------------------------------------------------------------------
// Init-GEMM role (proven R2 body, rowBase param): Y = X@W + b, fp32 in, bf16 out.
// ---------------------------------------------------------------------------
static __device__ inline void gemm_init_role(
    bf16_t* Wt, const float* __restrict__ X, const bf16_t* __restrict__ Wg,
    const float* __restrict__ B, bf16_t* __restrict__ Y, int M, int rowBase, int tid)
{
    stage_wbf<512>(Wt, Wg, tid);
    __syncthreads();

    const int wave = tid >> 6, lane = tid & 63;
    const int quad = lane >> 4, ln16 = lane & 15;
    const int row_l = wave * 16 + ln16;
    const int rowg = rowBase + row_l;
    const int rowc = rowg < M ? rowg : 0;

    bfvec8 xb[4];
    const float* xp = X + (size_t)rowc * CDIM + quad * 8;
    #pragma unroll
    for (int kc = 0; kc < 4; ++kc) {
        f32x4 lo = *reinterpret_cast<const f32x4*>(xp + kc * 32);
        f32x4 hi = *reinterpret_cast<const f32x4*>(xp + kc * 32 + 4);
        #pragma unroll
        for (int j = 0; j < 4; ++j) {
            xb[kc][j]     = (bf16_t)lo[j];
            xb[kc][j + 4] = (bf16_t)hi[j];
        }
    }

    f32x4 acc[8];
    #pragma unroll
    for (int t = 0; t < 8; ++t) acc[t] = (f32x4){0.f, 0.f, 0.f, 0.f};
    #pragma unroll
    for (int t = 0; t < 8; ++t) {
        const bf16_t* wp = &Wt[(t * 16 + ln16) * LDW + quad * 8];
        #pragma unroll
        for (int kc = 0; kc < 4; ++kc) {
            bfvec8 wv = *reinterpret_cast<const bfvec8*>(wp + kc * 32);
            acc[t] = __builtin_amdgcn_mfma_f32_16x16x32_bf16(wv, xb[kc], acc[t], 0, 0, 0);
        }
    }

    if (rowg < M) {
        #pragma unroll
        for (int t = 0; t < 8; ++t) {
            f32x4 bv = *reinterpret_cast<const f32x4*>(&B[t * 16 + quad * 4]);
            bfvec4 o;
            #pragma unroll
            for (int r = 0; r < 4; ++r) o[r] = (bf16_t)(acc[t][r] + bv[r]);
            *reinterpret_cast<bfvec4*>(&Y[(size_t)rowg * CDIM + t * 16 + quad * 4]) = o;
        }
    }
}

// ---------------------------------------------------------------------------
// FUSE_A: gemm_init(users) + gemm_init(items) + hist_rank, one kernel.
// Independent work; MFMA blocks overlap the atomic-bound histogram.
// ---------------------------------------------------------------------------
__global__ __launch_bounds__(512) void fuse_a(
    const float* __restrict__ x_user, const float* __restrict__ x_item,
    const bf16_t* __restrict__ wtg, const float* __restrict__ b_init,
    bf16_t* __restrict__ xub, bf16_t* __restrict__ xib,
    const int* __restrict__ edge_ui, const int* __restrict__ edge_iu,
    int* __restrict__ deg, int2* __restrict__ rank2)
{
    __shared__ __align__(16) bf16_t Wt[128 * LDW];
    int b = blockIdx.x, tid = threadIdx.x;
    if (b < GU) {
        gemm_init_role(Wt, x_user, wtg, b_init, xub, N_USER, b * 128, tid);
    } else if (b < GU + GI) {
        gemm_init_role(Wt, x_item, wtg + 16384, b_init + 128, xib, N_ITEM, (b - GU) * 128, tid);
    } else {
        int i = (b - GU - GI) * 512 + tid;
        if (i < NEDGE) {
            int r0 = atomicAdd(&deg[edge_ui[NEDGE + i]], 1);
            int r1 = atomicAdd(&deg[N_ITEM + edge_iu[NEDGE + i]], 1);
            rank2[i] = make_int2(r0, r1);
        }
    }
}

// ---------------------------------------------------------------------------
// CSR scan pieces (proven)
// ---------------------------------------------------------------------------
__global__ __launch_bounds__(256) void zero_i32(int* __restrict__ p, int n)
{
    int i = blockIdx.x * 256 + threadIdx.x;
    if (i < n) p[i] = 0;
}

__global__ __launch_bounds__(256) void block_scan(
    int* __restrict__ off, int* __restrict__ bsum, int n)
{
    __shared__ int sh[256];
    int tid = threadIdx.x;
    int i = blockIdx.x * 256 + tid;
    int v = (i < n) ? off[i] : 0;
    sh[tid] = v;
    __syncthreads();
    #pragma unroll
    for (int d = 1; d < 256; d <<= 1) {
        int t = (tid >= d) ? sh[tid - d] : 0;
        __syncthreads();
        sh[tid] += t;
        __syncthreads();
    }
    if (i < n) off[i] = sh[tid] - v;
    if (tid == 255) bsum[blockIdx.x] = sh[255];
}

__global__ __launch_bounds__(1024) void scan_bsums(int* __restrict__ bsum)
{
    __shared__ int sh[1024];
    int tid = threadIdx.x;
    int v = (tid < NB_SCAN) ? bsum[tid] : 0;
    sh[tid] = v;
    __syncthreads();
    #pragma unroll
    for (int d = 1; d < 1024; d <<= 1) {
        int t = (tid >= d) ? sh[tid - d] : 0;
        __syncthreads();
        sh[tid] += t;
        __syncthreads();
    }
    if (tid < NB_SCAN) bsum[tid] = sh[tid] - v;
    if (tid == 1023) bsum[NB_SCAN] = sh[1023];
}

__global__ __launch_bounds__(256) void add_offsets(
    int* __restrict__ off, const int* __restrict__ bsum, int n)
{
    int i = blockIdx.x * 256 + threadIdx.x;
    if (i < n) off[i] += bsum[i >> 8];
    else if (i == n) off[n] = bsum[NB_SCAN];
}

// ---------------------------------------------------------------------------
// Atomic-free, XCD-sliced CSR fill (proven R1).
// ---------------------------------------------------------------------------
__global__ __launch_bounds__(256) void fill_sliced(
    const int* __restrict__ edge_ui, const int* __restrict__ edge_iu,
    const int* __restrict__ off, const int2* __restrict__ rank2,
    int* __restrict__ srcbuf)
{
    const int r = blockIdx.x & 7;
    const int chunk = blockIdx.x >> 3;
    const int base = chunk * FILL_EPB + threadIdx.x;
    #pragma unroll
    for (int j = 0; j < FILL_EPB / 256; ++j) {
        int i = base + j * 256;
        if (i < NEDGE) {
            int d0 = edge_ui[NEDGE + i];
            int d1 = edge_iu[NEDGE + i] + N_ITEM;
            int2 rk = rank2[i];
            if (d0 / SLICE_DIV == r)
                srcbuf[off[d0] + rk.x] = edge_ui[i];
            if (d1 / SLICE_DIV == r)
                srcbuf[off[d1] + rk.y] = edge_iu[i];
        }
    }
}

// ---------------------------------------------------------------------------
// Gather role (proven R3 structure): one node per wave, 4 groups x 16 lanes x
// bfvec8. PURE AGGREGATE (self-combine moved to MLP input). Output bf16 or
// fp32 (flag). No LDS, no barriers -> safe in fused kernels.
// ---------------------------------------------------------------------------
static __device__ inline void gather_role(
    const bfvec8* __restrict__ F, const int* __restrict__ off,
    const int* __restrict__ srcbuf,
    bf16_t* __restrict__ outB, float* __restrict__ outF, int f32out,
    int M, int nodeBase, int tid)
{
    int wave = tid >> 6, lane = tid & 63;
    int grp = lane >> 4, l16 = lane & 15;
    int node = nodeBase + wave;
    if (node >= M) return;

    int start = off[node], end = off[node + 1];
    float acc[8];
    #pragma unroll
    for (int j = 0; j < 8; ++j) acc[j] = 0.f;

    int e = start + grp;
    for (; e + 12 < end; e += 16) {
        int s0 = srcbuf[e];
        int s1 = srcbuf[e + 4];
        int s2 = srcbuf[e + 8];
        int s3 = srcbuf[e + 12];
        bfvec8 v0 = F[(size_t)s0 * 16 + l16];
        bfvec8 v1 = F[(size_t)s1 * 16 + l16];
        bfvec8 v2 = F[(size_t)s2 * 16 + l16];
        bfvec8 v3 = F[(size_t)s3 * 16 + l16];
        #pragma unroll
        for (int j = 0; j < 8; ++j)
            acc[j] += ((float)v0[j] + (float)v1[j]) + ((float)v2[j] + (float)v3[j]);
    }
    for (; e + 4 < end; e += 8) {
        int s0 = srcbuf[e];
        int s1 = srcbuf[e + 4];
        bfvec8 v0 = F[(size_t)s0 * 16 + l16];
        bfvec8 v1 = F[(size_t)s1 * 16 + l16];
        #pragma unroll
        for (int j = 0; j < 8; ++j) acc[j] += (float)v0[j] + (float)v1[j];
    }
    for (; e < end; e += 4) {
        bfvec8 v = F[(size_t)srcbuf[e] * 16 + l16];
        #pragma unroll
        for (int j = 0; j < 8; ++j) acc[j] += (float)v[j];
    }

    #pragma unroll
    for (int j = 0; j < 8; ++j) {
        acc[j] += __shfl_xor(acc[j], 16, 64);
        acc[j] += __shfl_xor(acc[j], 32, 64);
    }

    if (grp == 0) {
        if (f32out) {
            f32x4 lo = (f32x4){acc[0], acc[1], acc[2], acc[3]};
            f32x4 hi = (f32x4){acc[4], acc[5], acc[6], acc[7]};
            float* p = outF + (size_t)node * CDIM + l16 * 8;
            *reinterpret_cast<f32x4*>(p)     = lo;
            *reinterpret_cast<f32x4*>(p + 4) = hi;
        } else {
            bfvec8 o;
            #pragma unroll
            for (int j = 0; j < 8; ++j) o[j] = (bf16_t)acc[j];
            reinterpret_cast<bfvec8*>(outB)[(size_t)node * 16 + l16] = o;
        }
    }
}

// ---------------------------------------------------------------------------
// MLP role (R2-proven MFMA/LN structure) with:
//  - GIN combine fused into input read: in = (1+eps)*self + agg
//  - SINGLE 34.8KB LDS buffer: H1 round-trips through Wt (GEMM1 -> barrier ->
//    H1 into Wt -> barrier -> hb regs -> barrier -> stage W2 -> GEMM2)
//  - agg source either bf16 or fp32 (flag), output bf16 or fp32 (flag)
// ---------------------------------------------------------------------------
static __device__ inline void mlp_role(
    bf16_t* Wt, int tid, int rowBase, int M,
    const bf16_t* __restrict__ AggB, const float* __restrict__ AggF, int aggF32,
    const bf16_t* __restrict__ Xself, const float* __restrict__ epsp,
    const bf16_t* __restrict__ W1g, const bf16_t* __restrict__ W2g,
    const float* __restrict__ B1, const float* __restrict__ B2,
    const float* __restrict__ G, const float* __restrict__ Bb,
    bf16_t* __restrict__ Yb, float* __restrict__ Yf, int f32out)
{
    stage_wbf<512>(Wt, W1g, tid);
    __syncthreads();

    const int wave = tid >> 6, lane = tid & 63;
    const int quad = lane >> 4, ln16 = lane & 15;
    const int row_l = wave * 16 + ln16;
    const int rowg = rowBase + row_l;
    const int rowc = rowg < M ? rowg : 0;
    const float s = 1.f + epsp[0];

    // input fragments: (1+eps)*self + agg, cast bf16
    bfvec8 xb[4];
    const bf16_t* xp = Xself + (size_t)rowc * CDIM + quad * 8;
    #pragma unroll
    for (int kc = 0; kc < 4; ++kc) {
        bfvec8 xv = *reinterpret_cast<const bfvec8*>(xp + kc * 32);
        float av[8];
        if (aggF32) {
            const float* ap = AggF + (size_t)rowc * CDIM + kc * 32 + quad * 8;
            f32x4 lo = *reinterpret_cast<const f32x4*>(ap);
            f32x4 hi = *reinterpret_cast<const f32x4*>(ap + 4);
            #pragma unroll
            for (int j = 0; j < 4; ++j) { av[j] = lo[j]; av[j + 4] = hi[j]; }
        } else {
            bfvec8 ab = *reinterpret_cast<const bfvec8*>(
                AggB + (size_t)rowc * CDIM + kc * 32 + quad * 8);
            #pragma unroll
            for (int j = 0; j < 8; ++j) av[j] = (float)ab[j];
        }
        #pragma unroll
        for (int j = 0; j < 8; ++j) xb[kc][j] = (bf16_t)(s * (float)xv[j] + av[j]);
    }

    // GEMM1
    f32x4 acc[8];
    #pragma unroll
    for (int t = 0; t < 8; ++t) acc[t] = (f32x4){0.f, 0.f, 0.f, 0.f};
    #pragma unroll
    for (int t = 0; t < 8; ++t) {
        const bf16_t* wp = &Wt[(t * 16 + ln16) * LDW + quad * 8];
        #pragma unroll
        for (int kc = 0; kc < 4; ++kc) {
            bfvec8 wv = *reinterpret_cast<const bfvec8*>(wp + kc * 32);
            acc[t] = __builtin_amdgcn_mfma_f32_16x16x32_bf16(wv, xb[kc], acc[t], 0, 0, 0);
        }
    }
    __syncthreads();                 // all W1 reads done

    // H1 (bias+ReLU) into Wt as [row][col] tile
    #pragma unroll
    for (int t = 0; t < 8; ++t) {
        f32x4 bv = *reinterpret_cast<const f32x4*>(&B1[t * 16 + quad * 4]);
        bfvec4 o;
        #pragma unroll
        for (int r = 0; r < 4; ++r) {
            float v = acc[t][r] + bv[r];
            o[r] = (bf16_t)(v > 0.f ? v : 0.f);
        }
        *reinterpret_cast<bfvec4*>(&Wt[row_l * LDW + t * 16 + quad * 4]) = o;
    }
    __syncthreads();

    // read own-row H1 fragments
    bfvec8 hb[4];
    #pragma unroll
    for (int kc = 0; kc < 4; ++kc)
        hb[kc] = *reinterpret_cast<const bfvec8*>(&Wt[row_l * LDW + kc * 32 + quad * 8]);
    __syncthreads();                 // all H1 reads done

    stage_wbf<512>(Wt, W2g, tid);
    __syncthreads();

    // GEMM2
    #pragma unroll
    for (int t = 0; t < 8; ++t) acc[t] = (f32x4){0.f, 0.f, 0.f, 0.f};
    #pragma unroll
    for (int t = 0; t < 8; ++t) {
        const bf16_t* wp = &Wt[(t * 16 + ln16) * LDW + quad * 8];
        #pragma unroll
        for (int kc = 0; kc < 4; ++kc) {
            bfvec8 wv = *reinterpret_cast<const bfvec8*>(wp + kc * 32);
            acc[t] = __builtin_amdgcn_mfma_f32_16x16x32_bf16(wv, hb[kc], acc[t], 0, 0, 0);
        }
    }

    #pragma unroll
    for (int t = 0; t < 8; ++t) {
        f32x4 bv = *reinterpret_cast<const f32x4*>(&B2[t * 16 + quad * 4]);
        #pragma unroll
        for (int r = 0; r < 4; ++r) {
            float v = acc[t][r] + bv[r];
            acc[t][r] = v > 0.f ? v : 0.f;
        }
    }

    // LayerNorm over own row (32 in-lane vals + 2 shuffles) + ReLU + store
    float sm = 0.f;
    #pragma unroll
    for (int t = 0; t < 8; ++t)
        #pragma unroll
        for (int r = 0; r < 4; ++r) sm += acc[t][r];
    sm += __shfl_xor(sm, 16, 64);
    sm += __shfl_xor(sm, 32, 64);
    float mean = sm * (1.f / 128.f);
    float sq = 0.f;
    #pragma unroll
    for (int t = 0; t < 8; ++t)
        #pragma unroll
        for (int r = 0; r < 4; ++r) { float d = acc[t][r] - mean; sq += d * d; }
    sq += __shfl_xor(sq, 16, 64);
    sq += __shfl_xor(sq, 32, 64);
    float rs = rsqrtf(sq * (1.f / 128.f) + 1e-5f);

    if (rowg < M) {
        if (f32out) {
            #pragma unroll
            for (int t = 0; t < 8; ++t) {
                f32x4 g4 = *reinterpret_cast<const f32x4*>(&G[t * 16 + quad * 4]);
                f32x4 b4 = *reinterpret_cast<const f32x4*>(&Bb[t * 16 + quad * 4]);
                f32x4 y;
                #pragma unroll
                for (int r = 0; r < 4; ++r) {
                    float v = (acc[t][r] - mean) * rs * g4[r] + b4[r];
                    y[r] = v > 0.f ? v : 0.f;
                }
                *reinterpret_cast<f32x4*>(&Yf[(size_t)rowg * CDIM + t * 16 + quad * 4]) = y;
            }
        } else {
            #pragma unroll
            for (int t = 0; t < 8; ++t) {
                f32x4 g4 = *reinterpret_cast<const f32x4*>(&G[t * 16 + quad * 4]);
                f32x4 b4 = *reinterpret_cast<const f32x4*>(&Bb[t * 16 + quad * 4]);
                bfvec4 y;
                #pragma unroll
                for (int r = 0; r < 4; ++r) {
                    float v = (acc[t][r] - mean) * rs * g4[r] + b4[r];
                    y[r] = (bf16_t)(v > 0.f ? v : 0.f);
                }
                *reinterpret_cast<bfvec4*>(&Yb[(size_t)rowg * CDIM + t * 16 + quad * 4]) = y;
            }
        }
    }
}

// ---------------------------------------------------------------------------
// Kernels built from the roles
// ---------------------------------------------------------------------------
// layer-0 gather, both types (pure agg, bf16 out)
__global__ __launch_bounds__(512) void gather0(
    const bf16_t* __restrict__ xub, const bf16_t* __restrict__ xib,
    const int* __restrict__ off_all, const int* __restrict__ srcbuf,
    bf16_t* __restrict__ tib, bf16_t* __restrict__ tub)
{
    int b = blockIdx.x, tid = threadIdx.x;
    if (b < GBI8)
        gather_role(reinterpret_cast<const bfvec8*>(xub), off_all, srcbuf,
                    tib, nullptr, 0, N_ITEM, b * 8, tid);
    else
        gather_role(reinterpret_cast<const bfvec8*>(xib), off_all + N_ITEM, srcbuf,
                    tub, nullptr, 0, N_USER, (b - GBI8) * 8, tid);
}

// standalone MLP (users)
__global__ __launch_bounds__(512, 6) void mlp_k(
    const bf16_t* __restrict__ AggB, const float* __restrict__ AggF, int aggF32,
    const bf16_t* __restrict__ Xself, const float* __restrict__ epsp,
    const bf16_t* __restrict__ W1g, const bf16_t* __restrict__ W2g,
    const float* __restrict__ B1, const float* __restrict__ B2,
    const float* __restrict__ G, const float* __restrict__ Bb,
    bf16_t* __restrict__ Yb, float* __restrict__ Yf, int f32out, int M)
{
    __shared__ __align__(16) bf16_t Wt[128 * LDW];
    mlp_role(Wt, threadIdx.x, blockIdx.x * 128, M, AggB, AggF, aggF32,
             Xself, epsp, W1g, W2g, B1, B2, G, Bb, Yb, Yf, f32out);
}

// FUSE_B: MLP items layer0 (tib,xib->xib)  ||  gather items layer1 (xub->tub)
__global__ __launch_bounds__(512, 6) void fuse_b(
    const bf16_t* __restrict__ tib, const bf16_t* __restrict__ xib_in,
    bf16_t* __restrict__ xib_out,
    const bf16_t* __restrict__ xub,
    const float* __restrict__ epsp,          // eps[0] (item, l0)
    const bf16_t* __restrict__ W1g, const bf16_t* __restrict__ W2g,
    const float* __restrict__ B1, const float* __restrict__ B2,
    const float* __restrict__ G, const float* __restrict__ Bb,
    const int* __restrict__ off_all, const int* __restrict__ srcbuf,
    bf16_t* __restrict__ t1i)
{
    __shared__ __align__(16) bf16_t Wt[128 * LDW];
    int b = blockIdx.x, tid = threadIdx.x;
    if (b < GI)
        mlp_role(Wt, tid, b * 128, N_ITEM, tib, nullptr, 0, xib_in, epsp,
                 W1g, W2g, B1, B2, G, Bb, xib_out, nullptr, 0);
    else
        gather_role(reinterpret_cast<const bfvec8*>(xub), off_all, srcbuf,
                    t1i, nullptr, 0, N_ITEM, (b - GI) * 8, tid);
}

// FUSE_C: MLP items layer1 (t1i,xib->xif fp32)  ||  gather users layer1 (xib->xuf fp32 agg)
__global__ __launch_bounds__(512, 6) void fuse_c(
    const bf16_t* __restrict__ t1i, const bf16_t* __restrict__ xib,
    float* __restrict__ xif,
    const float* __restrict__ epsp,          // eps[2] (item, l1)
    const bf16_t* __restrict__ W1g, const bf16_t* __restrict__ W2g,
    const float* __restrict__ B1, const float* __restrict__ B2,
    const float* __restrict__ G, const float* __restrict__ Bb,
    const int* __restrict__ off_all, const int* __restrict__ srcbuf,
    float* __restrict__ xuf_agg)
{
    __shared__ __align__(16) bf16_t Wt[128 * LDW];
    int b = blockIdx.x, tid = threadIdx.x;
    if (b < GI)
        mlp_role(Wt, tid, b * 128, N_ITEM, t1i, nullptr, 0, xib, epsp,
                 W1g, W2g, B1, B2, G, Bb, nullptr, xif, 1);
    else
        gather_role(reinterpret_cast<const bfvec8*>(xib), off_all + N_ITEM, srcbuf,
                    nullptr, xuf_agg, 1, N_USER, (b - GI) * 8, tid);
}

// ---------------------------------------------------------------------------
extern "C" void kernel_launch(void* const* d_in, const int* in_sizes, int n_in,
                              void* d_out, int out_size, void* d_ws, size_t ws_size,
                              hipStream_t stream)
{
    const float* x_user = (const float*)d_in[0];
    const float* x_item = (const float*)d_in[1];
    const float* W_init = (const float*)d_in[2];
    const float* b_init = (const float*)d_in[3];
    const float* mlp_W  = (const float*)d_in[4];
    const float* mlp_b  = (const float*)d_in[5];
    const float* eps    = (const float*)d_in[6];
    const float* ln_g   = (const float*)d_in[7];
    const float* ln_b   = (const float*)d_in[8];
    const int* edge_ui  = (const int*)d_in[9];
    const int* edge_iu  = (const int*)d_in[10];

    float* xuf = (float*)d_out;                     // [N_USER,128] fp32 out
    float* xif = xuf + (size_t)N_USER * CDIM;       // [N_ITEM,128]

    char* w = (char*)d_ws;
    bf16_t* xub = (bf16_t*)w;                                  // 25.6 MB
    bf16_t* xib = xub + (size_t)N_USER * CDIM;                 // 12.8 MB
    bf16_t* tub = xib + (size_t)N_ITEM * CDIM;                 // 25.6 MB (agg0u, then t1i)
    bf16_t* tib = tub + (size_t)N_USER * CDIM;                 // 12.8 MB (agg0i)
    int* off_all = (int*)(tib + (size_t)N_ITEM * CDIM);        // N_SEG+1
    int* bsum    = off_all + (N_SEG + 4);
    int* srcbuf  = bsum + (NB_SCAN + 2);                       // 2*NEDGE
    bf16_t* wtg  = (bf16_t*)(srcbuf + 2 * NEDGE);              // 10*16384 bf16

    // rank2 aliases tub: live only fuse_a -> fill_sliced (tub first written by gather0)
    int2* rank2 = (int2*)tub;

    const int gSeg = (N_SEG + 256) / 256;

    // weight offsets: wtg m = 2 + l*4 + edge*2 + nn  (edge0=item-dst, edge1=user-dst)
    const bf16_t* Wi0_1 = wtg + (size_t)2 * 16384;
    const bf16_t* Wi0_2 = wtg + (size_t)3 * 16384;
    const bf16_t* Wu0_1 = wtg + (size_t)4 * 16384;
    const bf16_t* Wu0_2 = wtg + (size_t)5 * 16384;
    const bf16_t* Wi1_1 = wtg + (size_t)6 * 16384;
    const bf16_t* Wi1_2 = wtg + (size_t)7 * 16384;
    const bf16_t* Wu1_1 = wtg + (size_t)8 * 16384;
    const bf16_t* Wu1_2 = wtg + (size_t)9 * 16384;

    prep_weights<<<640, 256, 0, stream>>>(W_init, mlp_W, wtg);
    zero_i32<<<(N_SEG + 255) / 256, 256, 0, stream>>>(off_all, N_SEG);

    // gemm_init(u) || gemm_init(i) || hist_rank
    fuse_a<<<GU + GI + GHIST, 512, 0, stream>>>(
        x_user, x_item, wtg, b_init, xub, xib, edge_ui, edge_iu, off_all, rank2);

    block_scan<<<NB_SCAN, 256, 0, stream>>>(off_all, bsum, N_SEG);
    scan_bsums<<<1, 1024, 0, stream>>>(bsum);
    add_offsets<<<gSeg, 256, 0, stream>>>(off_all, bsum, N_SEG);
    fill_sliced<<<FILL_NCHUNK * 8, 256, 0, stream>>>(edge_ui, edge_iu, off_all, rank2, srcbuf);

    // layer-0 gathers (pure agg): items<-xub, users<-xib
    gather0<<<GBI8 + GBU8, 512, 0, stream>>>(xub, xib, off_all, srcbuf, tib, tub);

    // M0u: users MLP l0 (tub,xub -> xub)
    mlp_k<<<GU, 512, 0, stream>>>(
        tub, nullptr, 0, xub, eps + 1, Wu0_1, Wu0_2,
        mlp_b + 256, mlp_b + 384, ln_g, ln_b, xub, nullptr, 0, N_USER);

    // M0i (tib,xib -> xib)  ||  G1i (xub -> t1i=tub)
    fuse_b<<<GI + GBI8, 512, 0, stream>>>(
        tib, xib, xib, xub, eps + 0, Wi0_1, Wi0_2,
        mlp_b + 0, mlp_b + 128, ln_g + 128, ln_b + 128,
        off_all, srcbuf, tub);

    // M1i (tub,xib -> xif fp32)  ||  G1u (xib -> xuf fp32 agg)
    fuse_c<<<GI + GBU8, 512, 0, stream>>>(
        tub, xib, xif, eps + 2, Wi1_1, Wi1_2,
        mlp_b + 512, mlp_b + 640, ln_g + 384, ln_b + 384,
        off_all, srcbuf, xuf);

    // M1u: users MLP l1 (xuf fp32 agg, xub self -> xuf fp32, in-place per-row)
    mlp_k<<<GU, 512, 0, stream>>>(
        nullptr, xuf, 1, xub, eps + 3, Wu1_1, Wu1_2,
        mlp_b + 768, mlp_b + 896, ln_g + 256, ln_b + 256,
        nullptr, xuf, 1, N_USER);
}